// Round 4
// baseline (923.546 us; speedup 1.0000x reference)
//
#include <hip/hip_runtime.h>

// 2-layer LSTM: B=2048, T=512, F=60, H=7, PyTorch gate order (i,f,g,o).
//
// FUSED producer-consumer kernel (v3): 512 blocks x 512 threads (8 waves).
//   waves 0..3 ("rec"):  one batch each. lanes 0..27 = layer0 gate rows at
//     step t (seed = A[b][t][r] from LDS); lanes 32..59 = layer1 gate rows at
//     step t-1 (seed = bias1). Per step: 1 ds_read seed (4-deep reg ring) +
//     2x dot7 + activation + 3 shfl gathers + cell update + 14 readlane
//     broadcasts. Identical math to the verified two-phase rec_kernel.
//   waves 4..7 ("proj"): one batch each. While rec consumes chunk c from
//     Abuf[c&1], proj computes chunk c+1 (64 rows x 28 gates, FMA order
//     identical to the verified proj v2 -> bit-identical seeds) into
//     Abuf[(c&1)^1]. x rows read per-lane (240 B contiguous/lane; L1 merges;
//     off the critical path). A never touches global memory (saves 234 MB
//     HBM round-trip + one kernel launch).
// LDS: Abuf 57,344 + wsm 6,720 + bsm 112 = 64,176 B -> 2 blocks/CU (16
// waves/CU), which the grid needs for a single tail-less pass (512 blocks).
// d_ws is unused.

#define B_ 2048
#define T_ 512
#define F_ 60
#define H_ 7
#define G4 28
#define L2E 1.4426950408889634f
#define PD 4            // seed prefetch ring depth (LDS)
#define CHK 64          // time-steps per producer chunk
#define NCHK (T_ / CHK) // 8

#if __has_builtin(__builtin_amdgcn_exp2f)
#define EXP2(x) __builtin_amdgcn_exp2f(x)
#else
#define EXP2(x) exp2f(x)
#endif

__device__ __forceinline__ float rcpf_(float v) { return __builtin_amdgcn_rcpf(v); }

__device__ __forceinline__ float bcast(float v, int srclane) {
    return __uint_as_float(__builtin_amdgcn_readlane(__float_as_uint(v), srclane));
}

__device__ __forceinline__ float dot7(const float* w, const float* h, float seed) {
    float m01 = fmaf(w[1], h[1], w[0] * h[0]);
    float m23 = fmaf(w[3], h[3], w[2] * h[2]);
    float m45 = fmaf(w[5], h[5], w[4] * h[4]);
    float m6  = fmaf(w[6], h[6], seed);
    return (m01 + m23) + (m45 + m6);
}

// Producer: one wave computes 64 rows (chunk ck) of batch bb into dst[64][28].
// Accumulation order identical to the verified proj v2 -> bit-identical A.
__device__ __forceinline__ void produce(const float* __restrict__ x,
                                        const float* __restrict__ wsm,
                                        const float* __restrict__ bsm,
                                        float (*__restrict__ dst)[G4],
                                        int bb, int ck, int lane)
{
    const float4* __restrict__ xp =
        (const float4*)(x + ((size_t)bb * T_ + ck * CHK + lane) * F_);
    float xr[F_];
    #pragma unroll
    for (int j = 0; j < 15; ++j) {
        float4 q = xp[j];
        xr[4 * j + 0] = q.x; xr[4 * j + 1] = q.y;
        xr[4 * j + 2] = q.z; xr[4 * j + 3] = q.w;
    }
    #pragma unroll
    for (int r = 0; r < G4; ++r) {
        const float* w = &wsm[r * F_];
        float a0 = bsm[r], a1 = 0.f, a2 = 0.f, a3 = 0.f;
        #pragma unroll
        for (int k = 0; k < F_; k += 4) {
            a0 = fmaf(w[k + 0], xr[k + 0], a0);
            a1 = fmaf(w[k + 1], xr[k + 1], a1);
            a2 = fmaf(w[k + 2], xr[k + 2], a2);
            a3 = fmaf(w[k + 3], xr[k + 3], a3);
        }
        dst[lane][r] = (a0 + a1) + (a2 + a3);
    }
}

__global__ __launch_bounds__(512, 4)
void lstm_fused(const float* __restrict__ x,
                const float* __restrict__ Wih0, const float* __restrict__ Whh0,
                const float* __restrict__ bih0, const float* __restrict__ bhh0,
                const float* __restrict__ Wih1, const float* __restrict__ Whh1,
                const float* __restrict__ bih1, const float* __restrict__ bhh1,
                float* __restrict__ out)
{
    __shared__ float Abuf[2][4][CHK][G4];   // 57,344 B seed double-buffer
    __shared__ float wsm[G4 * F_];          // 6,720 B Wih0
    __shared__ float bsm[G4];               // bias0

    const int tid   = threadIdx.x;
    const int lane  = tid & 63;
    const int wv    = tid >> 6;             // 0..7
    const bool isRec = (wv < 4);
    const int  bw   = wv & 3;               // batch-in-block (both roles)
    const int  b    = blockIdx.x * 4 + bw;

    // ---- producer setup: stage Wih0 + bias0 (proj waves = threads 256..511)
    if (!isRec) {
        const int tp = tid - 256;
        for (int i = tp; i < G4 * F_; i += 256) wsm[i] = Wih0[i];
        if (tp < G4) bsm[tp] = bih0[tp] + bhh0[tp];
    }

    // ---- rec setup (verbatim from the verified rec_kernel)
    const bool isL1 = lane >= 32;
    const int  g    = lane & 31;
    const int  r    = (g < G4) ? g : (G4 - 1);

    float wA[H_], wB[H_];
    float bias1 = 0.f;
    float h0v[H_] = {0, 0, 0, 0, 0, 0, 0};
    float h1v[H_] = {0, 0, 0, 0, 0, 0, 0};
    float c = 0.f, hnew = 0.f;
    const bool isT = (r >= 2 * H_ && r < 3 * H_);   // cell gate -> tanh
    const float KK = isT ? (-2.f * L2E) : (-L2E);
    const float Aa = isT ? 2.f : 1.f;
    const float Ca = isT ? -1.f : 0.f;

    if (isRec) {
        #pragma unroll
        for (int v = 0; v < H_; ++v) {
            wA[v] = isL1 ? Wih1[r * H_ + v] : Whh0[r * H_ + v];
            wB[v] = isL1 ? Whh1[r * H_ + v] : 0.f;
        }
        bias1 = bih1[r] + bhh1[r];
    }

    __syncthreads();   // #1: wsm/bsm ready

    if (!isRec) produce(x, wsm, bsm, Abuf[0][bw], b, 0, lane);
    __syncthreads();   // #2: chunk 0 seeds ready

    for (int ck = 0; ck < NCHK; ++ck) {
        const int pb = ck & 1;
        if (isRec) {
            const float* __restrict__ Ab = &Abuf[pb][bw][0][r];
            float sbuf[PD];
            #pragma unroll
            for (int i = 0; i < PD; ++i) sbuf[i] = Ab[i * G4];

            for (int tt = 0; tt < CHK; tt += PD) {
                #pragma unroll
                for (int s = 0; s < PD; ++s) {
                    const int tl = tt + s;
                    const int tn = (tl + PD < CHK) ? (tl + PD) : (CHK - 1);
                    float nb = Ab[tn * G4];          // prefetch (off-path)
                    const int t = ck * CHK + tl;     // global step

                    float seed = isL1 ? bias1 : sbuf[s];
                    float a = dot7(wA, h0v, seed);
                    a = dot7(wB, h1v, a);
                    float act = fmaf(Aa, rcpf_(1.f + EXP2(KK * a)), Ca);

                    float fg = __shfl(act, lane + 7, 64);
                    float gg = __shfl(act, lane + 14, 64);
                    float og = __shfl(act, lane + 21, 64);

                    float cnew = fmaf(fg, c, act * gg);
                    if (t == 0) cnew = isL1 ? 0.f : cnew;   // L1 phantom step
                    c = cnew;
                    float th = fmaf(2.f, rcpf_(1.f + EXP2(-2.f * L2E * c)), -1.f);
                    hnew = og * th;
                    // (t==0: L1 hnew = 0 -> broadcasts correct initial h1)

                    #pragma unroll
                    for (int v = 0; v < H_; ++v) h0v[v] = bcast(hnew, v);
                    #pragma unroll
                    for (int v = 0; v < H_; ++v) h1v[v] = bcast(hnew, 32 + v);

                    sbuf[s] = nb;
                }
            }
        } else if (ck + 1 < NCHK) {
            produce(x, wsm, bsm, Abuf[pb ^ 1][bw], b, ck + 1, lane);
        }
        __syncthreads();   // chunk ck consumed / chunk ck+1 produced
    }

    if (isRec) {
        // epilogue: layer1 step T-1 (consumes h0(T-1), h1(T-2))
        float a = dot7(wA, h0v, isL1 ? bias1 : 0.f);
        a = dot7(wB, h1v, a);
        float act = fmaf(Aa, rcpf_(1.f + EXP2(KK * a)), Ca);
        float fg = __shfl(act, lane + 7, 64);
        float gg = __shfl(act, lane + 14, 64);
        float og = __shfl(act, lane + 21, 64);
        c = fmaf(fg, c, act * gg);
        float th = fmaf(2.f, rcpf_(1.f + EXP2(-2.f * L2E * c)), -1.f);
        hnew = og * th;

        if (isL1 && g < H_) out[(size_t)b * H_ + g] = hnew;
    }
}

extern "C" void kernel_launch(void* const* d_in, const int* in_sizes, int n_in,
                              void* d_out, int out_size, void* d_ws, size_t ws_size,
                              hipStream_t stream) {
    const float* x    = (const float*)d_in[0];
    const float* Wih0 = (const float*)d_in[1];
    const float* Whh0 = (const float*)d_in[2];
    const float* bih0 = (const float*)d_in[3];
    const float* bhh0 = (const float*)d_in[4];
    const float* Wih1 = (const float*)d_in[5];
    const float* Whh1 = (const float*)d_in[6];
    const float* bih1 = (const float*)d_in[7];
    const float* bhh1 = (const float*)d_in[8];
    float* out = (float*)d_out;

    lstm_fused<<<dim3(B_ / 4), dim3(512), 0, stream>>>(
        x, Wih0, Whh0, bih0, bhh0, Wih1, Whh1, bih1, bhh1, out);
}